// Round 11
// baseline (431.837 us; speedup 1.0000x reference)
//
#include <hip/hip_runtime.h>
#include <hip/hip_fp16.h>

#define NVOX 65536
#define KVOL 125
#define NPAIR 1048576
#define CAP 48            // per-voxel bin capacity; counts ~ Poisson(16)
#define NBUCK 1024        // 64 voxels per bucket
#define BCAP 1280         // bucket capacity: mean 977 + ~9.7 sigma
#define QKV_BLOCKS 768
#define P1_BLOCKS 2048
#define GATH_BLOCKS 1024  // = NVOX/64, 4/CU, all co-resident

__device__ __forceinline__ float rdlane(float v, int j) {
    return __int_as_float(__builtin_amdgcn_readlane(__float_as_int(v), j));
}

// ---------------------------------------------------------------------------
// qkv projection + per-head L2 norm, fp16 outputs. Also zeroes the bucket
// counters for pass1 (stream order guarantees completion before pass1).
// ---------------------------------------------------------------------------
__global__ __launch_bounds__(256, 3) void qkv_kernel(
    const float* __restrict__ x,
    const float* __restrict__ Wq, const float* __restrict__ bq,
    const float* __restrict__ Wk, const float* __restrict__ bk,
    const float* __restrict__ Wv, const float* __restrict__ bv,
    __half* __restrict__ nqh, unsigned int* __restrict__ kv,
    int* __restrict__ bcur)
{
    __shared__ float wt[3 * 64 * 68];   // W^T per matrix: [m][c][j], stride 68
    const int tid  = threadIdx.x;
    const int lane = tid & 63;
    const int wid  = tid >> 6;
    const int gt   = blockIdx.x * 256 + tid;
    if (gt < NBUCK) bcur[gt] = 0;

    for (int idx = tid; idx < 3 * 4096; idx += 256) {
        const int m = idx >> 12;
        const int r = idx & 4095;
        const int j = r >> 6;
        const int c = r & 63;
        const float wv = (m == 0 ? Wq : (m == 1 ? Wk : Wv))[j * 64 + c];
        wt[(m * 64 + c) * 68 + j] = wv;
    }
    __syncthreads();

    const float* wtm0 = &wt[(0   + lane) * 68];
    const float* wtm1 = &wt[(64  + lane) * 68];
    const float* wtm2 = &wt[(128 + lane) * 68];
    const float bqv = bq[lane], bkv = bk[lane], bvv = bv[lane];
    const int t  = lane & 3;
    const int s0 = (lane & ~3) | ((t & 1) << 1);
    const int gw = blockIdx.x * 4 + wid;       // 3072 waves

    for (int nb = gw * 4; nb < NVOX; nb += QKV_BLOCKS * 16) {
        float xv[4], aq[4], ak[4], av[4];
        #pragma unroll
        for (int v = 0; v < 4; ++v) {
            xv[v] = x[(size_t)(nb + v) * 64 + lane];
            aq[v] = bqv; ak[v] = bkv; av[v] = bvv;
        }
        #pragma unroll 4
        for (int jb = 0; jb < 16; ++jb) {
            const int j = jb * 4;
            const float4 w0 = *(const float4*)&wtm0[j];
            const float4 w1 = *(const float4*)&wtm1[j];
            const float4 w2 = *(const float4*)&wtm2[j];
            #pragma unroll
            for (int v = 0; v < 4; ++v) {
                const float xj0 = rdlane(xv[v], j + 0);
                const float xj1 = rdlane(xv[v], j + 1);
                const float xj2 = rdlane(xv[v], j + 2);
                const float xj3 = rdlane(xv[v], j + 3);
                aq[v] += xj0 * w0.x + xj1 * w0.y + xj2 * w0.z + xj3 * w0.w;
                ak[v] += xj0 * w1.x + xj1 * w1.y + xj2 * w1.z + xj3 * w1.w;
                av[v] += xj0 * w2.x + xj1 * w2.y + xj2 * w2.z + xj3 * w2.w;
            }
        }
        #pragma unroll
        for (int v = 0; v < 4; ++v) {
            float sq = aq[v] * aq[v];
            float sk = ak[v] * ak[v];
            #pragma unroll
            for (int m = 1; m <= 8; m <<= 1) {
                sq += __shfl_xor(sq, m);
                sk += __shfl_xor(sk, m);
            }
            const float inq = aq[v] / fmaxf(sqrtf(sq), 1e-12f);
            const float ink = ak[v] / fmaxf(sqrtf(sk), 1e-12f);
            nqh[(size_t)(nb + v) * 64 + lane] = __float2half(inq);
            const unsigned hk = __half_as_ushort(__float2half(ink));
            const unsigned hv = __half_as_ushort(__float2half(av[v]));
            const unsigned combo = hk | (hv << 16);
            const unsigned g0 = (unsigned)__shfl((int)combo, s0);
            const unsigned g1 = (unsigned)__shfl((int)combo, s0 + 1);
            const unsigned b0 = (t >= 2) ? (g0 >> 16) : (g0 & 0xffffu);
            const unsigned b1 = (t >= 2) ? (g1 >> 16) : (g1 & 0xffffu);
            kv[(size_t)(nb + v) * 64 + lane] = b0 | (b1 << 16);
        }
    }
}

// ---------------------------------------------------------------------------
// pass1: coarse-bucket pairs by out>>6. Consecutive tickets -> consecutive
// addresses -> dense full-line writes (4 MB vs 64 MB random). +posnorm.
// Payload: (pk << 6) | (out & 63), pk = (inv<<7)|kidx  (29 bits total).
// ---------------------------------------------------------------------------
__global__ __launch_bounds__(256) void pass1_kernel(
    const float* __restrict__ pos, const int* __restrict__ kq_map,
    __half* __restrict__ nposh, int* __restrict__ bcur,
    unsigned int* __restrict__ buckets)
{
    const int tid  = threadIdx.x;
    const int lane = tid & 63;
    const int wid  = tid >> 6;
    if (blockIdx.x < KVOL && wid == 0) {
        const float pv = pos[blockIdx.x * 64 + lane];
        float s = pv * pv;
        #pragma unroll
        for (int m = 1; m <= 8; m <<= 1) s += __shfl_xor(s, m);
        nposh[blockIdx.x * 64 + lane] = __float2half(pv / fmaxf(sqrtf(s), 1e-12f));
    }
    const int gtid = blockIdx.x * 256 + tid;            // 0..524287
    #pragma unroll
    for (int h = 0; h < 2; ++h) {
        const int p = gtid + h * 524288;
        const unsigned kq0 = (unsigned)kq_map[p];
        const int out = kq_map[NPAIR + p];
        const unsigned inv = kq0 / 125u;
        const unsigned pk = (inv << 7) | (kq0 - inv * 125u);
        const int b = out >> 6;
        const int t = atomicAdd(&bcur[b], 1);
        if (t < BCAP) buckets[(size_t)b * BCAP + t] = (pk << 6) | (unsigned)(out & 63);
    }
}

// ---------------------------------------------------------------------------
// Gather + attention + Wo projection + residual. Block b owns voxels
// [b*64, b*64+64): stages its bucket, bins into LDS (LDS atomics), pair loop
// reads bins from LDS. fp16 Wo + shuffle epilogue -> 37.1 KB LDS -> 4/CU.
// ---------------------------------------------------------------------------
__device__ __forceinline__ void pair_accum(
    unsigned pk, const uint4& u, const __half* npos_s, int cc,
    const float4& a4, float4& ac)
{
    const int kidx = (int)(pk & 127u);
    const float2 k01 = __half22float2(*(const __half2*)&u.x);
    const float2 k23 = __half22float2(*(const __half2*)&u.y);
    const float2 v01 = __half22float2(*(const __half2*)&u.z);
    const float2 v23 = __half22float2(*(const __half2*)&u.w);
    const __half2* np = (const __half2*)&npos_s[kidx * 64 + cc];
    const float2 c01 = __half22float2(np[0]);
    const float2 c23 = __half22float2(np[1]);
    float pdot = a4.x * (k01.x + c01.x) + a4.y * (k01.y + c01.y)
               + a4.z * (k23.x + c23.x) + a4.w * (k23.y + c23.y);
    pdot += __shfl_xor(pdot, 1);
    pdot += __shfl_xor(pdot, 2);
    ac.x += pdot * v01.x; ac.y += pdot * v01.y;
    ac.z += pdot * v23.x; ac.w += pdot * v23.y;
}

__global__ __launch_bounds__(256, 4) void gather_out_kernel(
    const int* __restrict__ bcur, const unsigned int* __restrict__ buckets,
    const __half* __restrict__ nqh, const unsigned int* __restrict__ kv,
    const __half* __restrict__ nposh,
    const float* __restrict__ Wo, const float* __restrict__ bo,
    const float* __restrict__ x, float* __restrict__ out)
{
    __shared__ __half wo_h[4096];            // 8 KB
    __shared__ __half npos_s[8192];          // 16 KB
    __shared__ unsigned bins[64 * CAP];      // 12 KB
    __shared__ int lcnt[64];                 // 256 B
    const int tid = threadIdx.x;
    for (int i = tid; i < 4096; i += 256) wo_h[i] = __float2half(Wo[i]);
    for (int i = tid; i < 1000; i += 256) ((uint4*)npos_s)[i] = ((const uint4*)nposh)[i];
    if (tid < 64) lcnt[tid] = 0;
    __syncthreads();

    // ---- stage + LDS-bin this block's bucket ----
    const int b = blockIdx.x;
    const int cntb = min(bcur[b], BCAP);
    for (int i = tid; i < cntb; i += 256) {
        const unsigned val = buckets[(size_t)b * BCAP + i];
        const int v = (int)(val & 63u);
        const int r = atomicAdd(&lcnt[v], 1);
        if (r < CAP) bins[v * CAP + r] = val >> 6;
    }
    __syncthreads();

    const int lane = tid & 63;
    const int wid  = tid >> 6;
    const int l    = lane & 15;
    const int pg   = lane >> 4;
    const int cc   = l * 4;
    const float4 bo4 = *(const float4*)&bo[cc];

    #pragma unroll
    for (int g = 0; g < 4; ++g) {
        const int vb = wid * 16 + g * 4;       // local voxel base
        float4 acc[4];
        // ---- pair phase: 4 voxels, LDS bins, register accumulation ----
        #pragma unroll
        for (int v = 0; v < 4; ++v) {
            const int vl = vb + v;
            const int n = b * 64 + vl;
            const uint2 qp = *(const uint2*)(nqh + (size_t)n * 64 + cc);
            const float2 q01 = __half22float2(*(const __half2*)&qp.x);
            const float2 q23 = __half22float2(*(const __half2*)&qp.y);
            const float4 a4 = make_float4(q01.x, q01.y, q23.x, q23.y);
            const int cnt = min(lcnt[vl], CAP);
            const unsigned* bp = &bins[vl * CAP];
            float4 ac = make_float4(0.f, 0.f, 0.f, 0.f);
            int p = pg;
            while (p + 4 < cnt) {          // 2 kv gathers in flight per slot
                const unsigned pk0 = bp[p];
                const unsigned pk1 = bp[p + 4];
                const uint4 u0 = *(const uint4*)(kv + (size_t)(pk0 >> 7) * 64 + cc);
                const uint4 u1 = *(const uint4*)(kv + (size_t)(pk1 >> 7) * 64 + cc);
                pair_accum(pk0, u0, npos_s, cc, a4, ac);
                pair_accum(pk1, u1, npos_s, cc, a4, ac);
                p += 8;
            }
            if (p < cnt) {
                const unsigned pk = bp[p];
                const uint4 u = *(const uint4*)(kv + (size_t)(pk >> 7) * 64 + cc);
                pair_accum(pk, u, npos_s, cc, a4, ac);
            }
            ac.x += __shfl_xor(ac.x, 16); ac.y += __shfl_xor(ac.y, 16);
            ac.z += __shfl_xor(ac.z, 16); ac.w += __shfl_xor(ac.w, 16);
            ac.x += __shfl_xor(ac.x, 32); ac.y += __shfl_xor(ac.y, 32);
            ac.z += __shfl_xor(ac.z, 32); ac.w += __shfl_xor(ac.w, 32);
            acc[v] = ac;   // every lane holds msg chunk (lane&15)
        }
        // ---- epilogue: out = msg @ Wo + bo + x; j range split across pg ----
        float4 o4[4];
        #pragma unroll
        for (int v = 0; v < 4; ++v) o4[v] = make_float4(0.f, 0.f, 0.f, 0.f);
        #pragma unroll
        for (int ib = 0; ib < 4; ++ib) {
            const int jc = pg * 4 + ib;        // msg chunk index (lane jc)
            float4 mq[4];
            #pragma unroll
            for (int v = 0; v < 4; ++v) {
                mq[v].x = __shfl(acc[v].x, jc);
                mq[v].y = __shfl(acc[v].y, jc);
                mq[v].z = __shfl(acc[v].z, jc);
                mq[v].w = __shfl(acc[v].w, jc);
            }
            #pragma unroll
            for (int tt = 0; tt < 4; ++tt) {
                const int j = jc * 4 + tt;
                const __half2* wp = (const __half2*)&wo_h[j * 64 + cc];
                const float2 wa = __half22float2(wp[0]);
                const float2 wb = __half22float2(wp[1]);
                #pragma unroll
                for (int v = 0; v < 4; ++v) {
                    const float m = (tt == 0 ? mq[v].x : tt == 1 ? mq[v].y :
                                     tt == 2 ? mq[v].z : mq[v].w);
                    o4[v].x += m * wa.x; o4[v].y += m * wa.y;
                    o4[v].z += m * wb.x; o4[v].w += m * wb.y;
                }
            }
        }
        #pragma unroll
        for (int v = 0; v < 4; ++v) {
            o4[v].x += __shfl_xor(o4[v].x, 16); o4[v].y += __shfl_xor(o4[v].y, 16);
            o4[v].z += __shfl_xor(o4[v].z, 16); o4[v].w += __shfl_xor(o4[v].w, 16);
            o4[v].x += __shfl_xor(o4[v].x, 32); o4[v].y += __shfl_xor(o4[v].y, 32);
            o4[v].z += __shfl_xor(o4[v].z, 32); o4[v].w += __shfl_xor(o4[v].w, 32);
        }
        if (pg == 0) {
            #pragma unroll
            for (int v = 0; v < 4; ++v) {
                const int n = b * 64 + vb + v;
                const float4 xr = *(const float4*)&x[(size_t)n * 64 + cc];
                float4 r;
                r.x = o4[v].x + bo4.x + xr.x;
                r.y = o4[v].y + bo4.y + xr.y;
                r.z = o4[v].z + bo4.z + xr.z;
                r.w = o4[v].w + bo4.w + xr.w;
                *(float4*)&out[(size_t)n * 64 + cc] = r;
            }
        }
    }
}

// ---------------------------------------------------------------------------
extern "C" void kernel_launch(void* const* d_in, const int* in_sizes, int n_in,
                              void* d_out, int out_size, void* d_ws, size_t ws_size,
                              hipStream_t stream) {
    const float* x   = (const float*)d_in[0];
    const float* Wq  = (const float*)d_in[1];
    const float* bq  = (const float*)d_in[2];
    const float* Wk  = (const float*)d_in[3];
    const float* bk  = (const float*)d_in[4];
    const float* Wv  = (const float*)d_in[5];
    const float* bv  = (const float*)d_in[6];
    const float* Wo  = (const float*)d_in[7];
    const float* bo  = (const float*)d_in[8];
    const float* pos = (const float*)d_in[9];
    const int*   kq  = (const int*)d_in[10];

    char* w = (char*)d_ws;
    unsigned int* kv      = (unsigned int*)w; w += (size_t)NVOX * 64 * 4;       // 16 MB
    __half*       nqh     = (__half*)w;       w += (size_t)NVOX * 64 * 2;       // 8 MB
    unsigned int* buckets = (unsigned int*)w; w += (size_t)NBUCK * BCAP * 4;    // 5.25 MB
    int*          bcur    = (int*)w;          w += (size_t)NBUCK * 4;           // 4 KB
    __half*       nposh   = (__half*)w;       w += 16384;                       // 16 KB

    qkv_kernel<<<QKV_BLOCKS, 256, 0, stream>>>(x, Wq, bq, Wk, bk, Wv, bv, nqh, kv, bcur);
    pass1_kernel<<<P1_BLOCKS, 256, 0, stream>>>(pos, kq, nposh, bcur, buckets);
    gather_out_kernel<<<GATH_BLOCKS, 256, 0, stream>>>(bcur, buckets, nqh, kv, nposh,
                                                       Wo, bo, x, (float*)d_out);
}

// Round 12
// 302.020 us; speedup vs baseline: 1.4298x; 1.4298x over previous
//
#include <hip/hip_runtime.h>
#include <hip/hip_fp16.h>

#define NVOX 65536
#define KVOL 125
#define NPAIR 1048576
#define CAP 48            // per-voxel bin capacity; counts ~ Poisson(16)
#define FILL_BLOCKS 2048
#define QKV_BLOCKS 768
#define GATH_BLOCKS 1024

__device__ __forceinline__ float rdlane(float v, int j) {
    return __int_as_float(__builtin_amdgcn_readlane(__float_as_int(v), j));
}

// ---------------------------------------------------------------------------
// qkv projection + per-head L2 norm. Outputs: nqh fp16, ktab int8 (k*127),
// vtab fp16 — all plain coalesced per-lane stores (no pack shuffles).
// Also zeroes cursor for fill (stream order guarantees visibility).
// ---------------------------------------------------------------------------
__global__ __launch_bounds__(256, 3) void qkv_kernel(
    const float* __restrict__ x,
    const float* __restrict__ Wq, const float* __restrict__ bq,
    const float* __restrict__ Wk, const float* __restrict__ bk,
    const float* __restrict__ Wv, const float* __restrict__ bv,
    __half* __restrict__ nqh, signed char* __restrict__ ktab,
    __half* __restrict__ vtab, int* __restrict__ cursor)
{
    __shared__ float wt[3 * 64 * 68];   // W^T per matrix: [m][c][j], stride 68
    const int tid  = threadIdx.x;
    const int lane = tid & 63;
    const int wid  = tid >> 6;
    const int gt   = blockIdx.x * 256 + tid;
    if (gt < NVOX) cursor[gt] = 0;

    for (int idx = tid; idx < 3 * 4096; idx += 256) {
        const int m = idx >> 12;
        const int r = idx & 4095;
        const int j = r >> 6;
        const int c = r & 63;
        const float wv = (m == 0 ? Wq : (m == 1 ? Wk : Wv))[j * 64 + c];
        wt[(m * 64 + c) * 68 + j] = wv;
    }
    __syncthreads();

    const float* wtm0 = &wt[(0   + lane) * 68];
    const float* wtm1 = &wt[(64  + lane) * 68];
    const float* wtm2 = &wt[(128 + lane) * 68];
    const float bqv = bq[lane], bkv = bk[lane], bvv = bv[lane];
    const int gw = blockIdx.x * 4 + wid;       // 3072 waves

    for (int nb = gw * 4; nb < NVOX; nb += QKV_BLOCKS * 16) {
        float xv[4], aq[4], ak[4], av[4];
        #pragma unroll
        for (int v = 0; v < 4; ++v) {
            xv[v] = x[(size_t)(nb + v) * 64 + lane];
            aq[v] = bqv; ak[v] = bkv; av[v] = bvv;
        }
        #pragma unroll 4
        for (int jb = 0; jb < 16; ++jb) {
            const int j = jb * 4;
            const float4 w0 = *(const float4*)&wtm0[j];
            const float4 w1 = *(const float4*)&wtm1[j];
            const float4 w2 = *(const float4*)&wtm2[j];
            #pragma unroll
            for (int v = 0; v < 4; ++v) {
                const float xj0 = rdlane(xv[v], j + 0);
                const float xj1 = rdlane(xv[v], j + 1);
                const float xj2 = rdlane(xv[v], j + 2);
                const float xj3 = rdlane(xv[v], j + 3);
                aq[v] += xj0 * w0.x + xj1 * w0.y + xj2 * w0.z + xj3 * w0.w;
                ak[v] += xj0 * w1.x + xj1 * w1.y + xj2 * w1.z + xj3 * w1.w;
                av[v] += xj0 * w2.x + xj1 * w2.y + xj2 * w2.z + xj3 * w2.w;
            }
        }
        #pragma unroll
        for (int v = 0; v < 4; ++v) {
            float sq = aq[v] * aq[v];
            float sk = ak[v] * ak[v];
            #pragma unroll
            for (int m = 1; m <= 8; m <<= 1) {
                sq += __shfl_xor(sq, m);
                sk += __shfl_xor(sk, m);
            }
            const float inq = aq[v] / fmaxf(sqrtf(sq), 1e-12f);
            const float ink = ak[v] / fmaxf(sqrtf(sk), 1e-12f);
            const size_t o = (size_t)(nb + v) * 64 + lane;
            nqh[o]  = __float2half(inq);
            ktab[o] = (signed char)__float2int_rn(ink * 127.f);
            vtab[o] = __float2half(av[v]);
        }
    }
}

// ---------------------------------------------------------------------------
// fill: per-voxel bins via 65536 cursor ticket atomics (+posnorm piggyback).
// (R10-proven; 1024-counter variants are atomic-contention bound — R11.)
// ---------------------------------------------------------------------------
__global__ __launch_bounds__(256) void fill_kernel(
    const float* __restrict__ pos, const int* __restrict__ kq_map,
    __half* __restrict__ nposh, int* __restrict__ cursor,
    unsigned int* __restrict__ pairlist)
{
    const int tid  = threadIdx.x;
    const int lane = tid & 63;
    const int wid  = tid >> 6;
    if (blockIdx.x < KVOL && wid == 0) {
        const float pv = pos[blockIdx.x * 64 + lane];
        float s = pv * pv;
        #pragma unroll
        for (int m = 1; m <= 8; m <<= 1) s += __shfl_xor(s, m);
        nposh[blockIdx.x * 64 + lane] = __float2half(pv / fmaxf(sqrtf(s), 1e-12f));
    }
    const int gtid = blockIdx.x * 256 + tid;            // 0..524287
    const int p0 = gtid;
    const int p1 = gtid + 524288;
    const unsigned k0 = (unsigned)kq_map[p0];
    const unsigned k1 = (unsigned)kq_map[p1];
    const int o0 = kq_map[NPAIR + p0];
    const int o1 = kq_map[NPAIR + p1];
    const int r0 = atomicAdd(&cursor[o0], 1);
    const int r1 = atomicAdd(&cursor[o1], 1);
    const unsigned i0 = k0 / 125u, i1 = k1 / 125u;
    if (r0 < CAP) pairlist[(size_t)o0 * CAP + r0] = (i0 << 7) | (k0 - i0 * 125u);
    if (r1 < CAP) pairlist[(size_t)o1 * CAP + r1] = (i1 << 7) | (k1 - i1 * 125u);
}

// ---------------------------------------------------------------------------
// Gather + attention + Wo projection + residual. int8 ktab (64B row = 1 line)
// + fp16 vtab (128B row = 2 lines) vs old 256B row = 4 lines. R10 epilogue.
// ---------------------------------------------------------------------------
__device__ __forceinline__ void pair_accum(
    unsigned pk, unsigned kk, uint2 vv, const __half* npos_s, int cc,
    const float4& a4, const float4& a4s, float4& ac)
{
    const int kidx = (int)(pk & 127u);
    const __half2* np = (const __half2*)&npos_s[kidx * 64 + cc];
    const float2 c01 = __half22float2(np[0]);
    const float2 c23 = __half22float2(np[1]);
    const int ki = (int)kk;
    const float k0 = (float)(signed char)(ki);
    const float k1 = (float)(signed char)(ki >> 8);
    const float k2 = (float)(signed char)(ki >> 16);
    const float k3 = (float)(ki >> 24);
    float pdot = a4s.x * k0 + a4s.y * k1 + a4s.z * k2 + a4s.w * k3
               + a4.x * c01.x + a4.y * c01.y + a4.z * c23.x + a4.w * c23.y;
    pdot += __shfl_xor(pdot, 1);
    pdot += __shfl_xor(pdot, 2);
    const float2 v01 = __half22float2(*(const __half2*)&vv.x);
    const float2 v23 = __half22float2(*(const __half2*)&vv.y);
    ac.x += pdot * v01.x; ac.y += pdot * v01.y;
    ac.z += pdot * v23.x; ac.w += pdot * v23.y;
}

__global__ __launch_bounds__(256, 4) void gather_out_kernel(
    const int* __restrict__ cursor, const unsigned int* __restrict__ pairlist,
    const __half* __restrict__ nqh, const signed char* __restrict__ ktab,
    const __half* __restrict__ vtab, const __half* __restrict__ nposh,
    const float* __restrict__ Wo, const float* __restrict__ bo,
    const float* __restrict__ x, float* __restrict__ out)
{
    __shared__ float wo_s[4096];
    __shared__ __half npos_s[8192];
    __shared__ float ms[4][4][64];
    const int tid = threadIdx.x;
    for (int i = tid; i < 1024; i += 256) ((float4*)wo_s)[i] = ((const float4*)Wo)[i];
    for (int i = tid; i < 1000; i += 256) ((uint4*)npos_s)[i] = ((const uint4*)nposh)[i];
    __syncthreads();

    const int lane = tid & 63;
    const int wid  = tid >> 6;
    const int l    = lane & 15;
    const int pg   = lane >> 4;
    const int cc   = l * 4;
    const int gw   = blockIdx.x * 4 + wid;   // 4096 waves
    const float4 bo4 = *(const float4*)&bo[cc];

    for (int nb = gw * 4; nb < NVOX; nb += GATH_BLOCKS * 16) {
        // ---- pair phase: 4 voxels, register accumulation ----
        #pragma unroll
        for (int v = 0; v < 4; ++v) {
            const int n = nb + v;
            const uint2 qp = *(const uint2*)(nqh + (size_t)n * 64 + cc);
            const float2 q01 = __half22float2(*(const __half2*)&qp.x);
            const float2 q23 = __half22float2(*(const __half2*)&qp.y);
            const float4 a4 = make_float4(q01.x, q01.y, q23.x, q23.y);
            const float4 a4s = make_float4(a4.x * (1.f / 127.f), a4.y * (1.f / 127.f),
                                           a4.z * (1.f / 127.f), a4.w * (1.f / 127.f));
            const int s = n * CAP;
            const int cnt = min(cursor[n], CAP);
            const int e = s + cnt;
            float4 acc = make_float4(0.f, 0.f, 0.f, 0.f);
            int p = s + pg;
            while (p + 4 < e) {        // 2 pairs in flight per slot
                const unsigned pk0 = pairlist[p];
                const unsigned pk1 = pairlist[p + 4];
                const unsigned kk0 = *(const unsigned*)(ktab + (size_t)(pk0 >> 7) * 64 + cc);
                const unsigned kk1 = *(const unsigned*)(ktab + (size_t)(pk1 >> 7) * 64 + cc);
                const uint2 vv0 = *(const uint2*)(vtab + (size_t)(pk0 >> 7) * 64 + cc);
                const uint2 vv1 = *(const uint2*)(vtab + (size_t)(pk1 >> 7) * 64 + cc);
                pair_accum(pk0, kk0, vv0, npos_s, cc, a4, a4s, acc);
                pair_accum(pk1, kk1, vv1, npos_s, cc, a4, a4s, acc);
                p += 8;
            }
            if (p < e) {
                const unsigned pk = pairlist[p];
                const unsigned kk = *(const unsigned*)(ktab + (size_t)(pk >> 7) * 64 + cc);
                const uint2 vv = *(const uint2*)(vtab + (size_t)(pk >> 7) * 64 + cc);
                pair_accum(pk, kk, vv, npos_s, cc, a4, a4s, acc);
            }
            acc.x += __shfl_xor(acc.x, 16); acc.y += __shfl_xor(acc.y, 16);
            acc.z += __shfl_xor(acc.z, 16); acc.w += __shfl_xor(acc.w, 16);
            acc.x += __shfl_xor(acc.x, 32); acc.y += __shfl_xor(acc.y, 32);
            acc.z += __shfl_xor(acc.z, 32); acc.w += __shfl_xor(acc.w, 32);
            if (pg == 0) *(float4*)&ms[wid][v][cc] = acc;
        }
        __syncthreads();
        // ---- epilogue: out = msg @ Wo + bo + x  (j split across quarters) ----
        float4 o4[4];
        #pragma unroll
        for (int v = 0; v < 4; ++v) o4[v] = make_float4(0.f, 0.f, 0.f, 0.f);
        #pragma unroll
        for (int ib = 0; ib < 4; ++ib) {
            float4 mq[4];
            #pragma unroll
            for (int v = 0; v < 4; ++v)
                mq[v] = *(const float4*)&ms[wid][v][pg * 16 + ib * 4];
            #pragma unroll
            for (int tt = 0; tt < 4; ++tt) {
                const int j = pg * 16 + ib * 4 + tt;
                const float4 w4 = *(const float4*)&wo_s[j * 64 + cc];
                #pragma unroll
                for (int v = 0; v < 4; ++v) {
                    const float m = (tt == 0 ? mq[v].x : tt == 1 ? mq[v].y :
                                     tt == 2 ? mq[v].z : mq[v].w);
                    o4[v].x += m * w4.x; o4[v].y += m * w4.y;
                    o4[v].z += m * w4.z; o4[v].w += m * w4.w;
                }
            }
        }
        #pragma unroll
        for (int v = 0; v < 4; ++v) {
            o4[v].x += __shfl_xor(o4[v].x, 16); o4[v].y += __shfl_xor(o4[v].y, 16);
            o4[v].z += __shfl_xor(o4[v].z, 16); o4[v].w += __shfl_xor(o4[v].w, 16);
            o4[v].x += __shfl_xor(o4[v].x, 32); o4[v].y += __shfl_xor(o4[v].y, 32);
            o4[v].z += __shfl_xor(o4[v].z, 32); o4[v].w += __shfl_xor(o4[v].w, 32);
        }
        if (pg == 0) {
            #pragma unroll
            for (int v = 0; v < 4; ++v) {
                const float4 xr = *(const float4*)&x[(size_t)(nb + v) * 64 + cc];
                float4 r;
                r.x = o4[v].x + bo4.x + xr.x;
                r.y = o4[v].y + bo4.y + xr.y;
                r.z = o4[v].z + bo4.z + xr.z;
                r.w = o4[v].w + bo4.w + xr.w;
                *(float4*)&out[(size_t)(nb + v) * 64 + cc] = r;
            }
        }
        __syncthreads();
    }
}

// ---------------------------------------------------------------------------
extern "C" void kernel_launch(void* const* d_in, const int* in_sizes, int n_in,
                              void* d_out, int out_size, void* d_ws, size_t ws_size,
                              hipStream_t stream) {
    const float* x   = (const float*)d_in[0];
    const float* Wq  = (const float*)d_in[1];
    const float* bq  = (const float*)d_in[2];
    const float* Wk  = (const float*)d_in[3];
    const float* bk  = (const float*)d_in[4];
    const float* Wv  = (const float*)d_in[5];
    const float* bv  = (const float*)d_in[6];
    const float* Wo  = (const float*)d_in[7];
    const float* bo  = (const float*)d_in[8];
    const float* pos = (const float*)d_in[9];
    const int*   kq  = (const int*)d_in[10];

    char* w = (char*)d_ws;
    __half*       nqh      = (__half*)w;       w += (size_t)NVOX * 64 * 2;    // 8 MB
    __half*       vtab     = (__half*)w;       w += (size_t)NVOX * 64 * 2;    // 8 MB
    signed char*  ktab     = (signed char*)w;  w += (size_t)NVOX * 64;        // 4 MB
    unsigned int* pairlist = (unsigned int*)w; w += (size_t)NVOX * CAP * 4;   // 12 MB
    int*          cursor   = (int*)w;          w += (size_t)NVOX * 4;         // 256 KB
    __half*       nposh    = (__half*)w;       w += 16384;                    // 16 KB

    qkv_kernel<<<QKV_BLOCKS, 256, 0, stream>>>(x, Wq, bq, Wk, bk, Wv, bv,
                                               nqh, ktab, vtab, cursor);
    fill_kernel<<<FILL_BLOCKS, 256, 0, stream>>>(pos, kq, nposh, cursor, pairlist);
    gather_out_kernel<<<GATH_BLOCKS, 256, 0, stream>>>(cursor, pairlist, nqh, ktab, vtab,
                                                       nposh, Wo, bo, x, (float*)d_out);
}